// Round 3
// baseline (432.665 us; speedup 1.0000x reference)
//
#include <hip/hip_runtime.h>
#include <math.h>

// ---------------------------------------------------------------------------
// MPNN forward (N=10000 nodes, E=40000 edges, B=250 graphs, H=64, RD=1024)
//
// Strategy:
//   W_edge = (efeat @ We.T + be)  is E x 64 x 64 (655MB) -- never materialize.
//   m[e,o] = sum_k efeat[e,k] * M[src[e], k*64+o],  M = h @ We2 (64 x 896),
//   where We2[:, k*64+o] packs We slice k (k<13) and be (k==13, efeat_k=1).
//   The GRU's gh = h @ whh.T shares the A operand with M, so B is the
//   concatenation [We2 | whhT] (64 x 1088) and gh lives at col 896 of M.
// ---------------------------------------------------------------------------

#define H 64
#define NODE_IN 74
#define EDGE_IN 12
#define EF 14            // EDGE_IN + gate + 1.0 (bias slot)
#define GCAP 256         // per-graph node-list capacity
#define MGH 1088         // fused M|gh row width (896 + 192)

__device__ __forceinline__ float sigmoidf(float x) {
    return 1.0f / (1.0f + expf(-x));
}

// ---------------------------------------------------------------------------
// Tiled f32 GEMM: C[M,N] = op_epi( op_a(A)[M,K] @ B[K,N] )
// A row-major lda, B row-major ldb (K x N), C row-major ldc.
// AOP==1: a := relu(a + abias[k])   (fused NNConv bias+relu on the A operand)
// EOP==1: c := prelu(c + cbias[n])  (final projection epilogue)
// Requires: K%64==0, N%64==0, lda%4==0. M guarded.
// ---------------------------------------------------------------------------
template<int AOP, int EOP>
__global__ __launch_bounds__(256)
void gemm_k(const float* __restrict__ A, int lda,
            const float* __restrict__ B, int ldb,
            float* __restrict__ C, int ldc,
            int M, int N, int K,
            const float* __restrict__ abias,
            const float* __restrict__ cbias,
            const float* __restrict__ prelu_a)
{
    __shared__ float sA[64][68];   // sA[k][m]  (transposed on load)
    __shared__ float sB[64][68];   // sB[k][n]

    const int tid = threadIdx.x;
    const int bm  = blockIdx.x * 64;
    const int bn  = blockIdx.y * 64;
    const int tx  = tid & 15;      // col group (4 cols each)
    const int ty  = tid >> 4;      // row group (4 rows each)

    float acc[4][4] = {{0.f}};

    for (int k0 = 0; k0 < K; k0 += 64) {
        // ---- load A tile (64 rows m, 64 cols k), transpose into sA[k][m]
        #pragma unroll
        for (int t = 0; t < 4; ++t) {
            int idx = tid + t * 256;        // float4 index 0..1023
            int r   = idx >> 4;             // m row 0..63
            int c   = (idx & 15) << 2;      // k col 0..60
            float4 v = {0.f, 0.f, 0.f, 0.f};
            int gm = bm + r;
            if (gm < M) {
                v = *reinterpret_cast<const float4*>(A + (size_t)gm * lda + (k0 + c));
                if (AOP == 1) {
                    v.x = fmaxf(v.x + abias[k0 + c + 0], 0.f);
                    v.y = fmaxf(v.y + abias[k0 + c + 1], 0.f);
                    v.z = fmaxf(v.z + abias[k0 + c + 2], 0.f);
                    v.w = fmaxf(v.w + abias[k0 + c + 3], 0.f);
                }
            }
            sA[c + 0][r] = v.x;
            sA[c + 1][r] = v.y;
            sA[c + 2][r] = v.z;
            sA[c + 3][r] = v.w;
        }
        // ---- load B tile (64 rows k, 64 cols n)
        #pragma unroll
        for (int t = 0; t < 4; ++t) {
            int idx = tid + t * 256;
            int r   = idx >> 4;             // k row
            int c   = (idx & 15) << 2;      // n col
            float4 v = *reinterpret_cast<const float4*>(B + (size_t)(k0 + r) * ldb + (bn + c));
            *reinterpret_cast<float4*>(&sB[r][c]) = v;
        }
        __syncthreads();

        #pragma unroll
        for (int kk = 0; kk < 64; ++kk) {
            float4 av = *reinterpret_cast<const float4*>(&sA[kk][ty * 4]);
            float4 bv = *reinterpret_cast<const float4*>(&sB[kk][tx * 4]);
            float a0 = av.x, a1 = av.y, a2 = av.z, a3 = av.w;
            float b0 = bv.x, b1 = bv.y, b2 = bv.z, b3 = bv.w;
            acc[0][0] = fmaf(a0, b0, acc[0][0]); acc[0][1] = fmaf(a0, b1, acc[0][1]);
            acc[0][2] = fmaf(a0, b2, acc[0][2]); acc[0][3] = fmaf(a0, b3, acc[0][3]);
            acc[1][0] = fmaf(a1, b0, acc[1][0]); acc[1][1] = fmaf(a1, b1, acc[1][1]);
            acc[1][2] = fmaf(a1, b2, acc[1][2]); acc[1][3] = fmaf(a1, b3, acc[1][3]);
            acc[2][0] = fmaf(a2, b0, acc[2][0]); acc[2][1] = fmaf(a2, b1, acc[2][1]);
            acc[2][2] = fmaf(a2, b2, acc[2][2]); acc[2][3] = fmaf(a2, b3, acc[2][3]);
            acc[3][0] = fmaf(a3, b0, acc[3][0]); acc[3][1] = fmaf(a3, b1, acc[3][1]);
            acc[3][2] = fmaf(a3, b2, acc[3][2]); acc[3][3] = fmaf(a3, b3, acc[3][3]);
        }
        __syncthreads();
    }

    float pa = (EOP == 1) ? prelu_a[0] : 0.f;
    #pragma unroll
    for (int i = 0; i < 4; ++i) {
        int gm = bm + ty * 4 + i;
        if (gm < M) {
            float4 v;
            float* vv = reinterpret_cast<float*>(&v);
            #pragma unroll
            for (int j = 0; j < 4; ++j) {
                float c = acc[i][j];
                if (EOP == 1) {
                    c += cbias[bn + tx * 4 + j];
                    c = (c >= 0.f) ? c : pa * c;
                }
                vv[j] = c;
            }
            *reinterpret_cast<float4*>(C + (size_t)gm * ldc + bn + tx * 4) = v;
        }
    }
}

// ---------------------------------------------------------------------------
// Fused prologue (block-range split):
//   [0, nb_h0)            h0 = relu(node_attr @ Wp.T + bp)
//   [nb_h0, +nb_prep)     weight re-layouts (We2b=[We2|whhT], wihT, WlT, WsT)
//   [.., +nb_deg)         in-degrees (atomic)
//   [.., +nb_gl)          per-graph node lists (atomic slots)
// ---------------------------------------------------------------------------
__global__ __launch_bounds__(256)
void prep_all_k(const float* __restrict__ na, const float* __restrict__ Wp,
                const float* __restrict__ bp, float* __restrict__ h0,
                const float* __restrict__ We, const float* __restrict__ be,
                const float* __restrict__ wih, const float* __restrict__ whh,
                const float* __restrict__ lwih, const float* __restrict__ lwhh,
                const float* __restrict__ Ws,
                float* __restrict__ We2b, float* __restrict__ wihT,
                float* __restrict__ WlT, float* __restrict__ WsT,
                const int* __restrict__ dst, float* __restrict__ deg,
                const int* __restrict__ gid, int* __restrict__ gcnt,
                int* __restrict__ glist,
                int N, int E,
                int nb_h0, int nb_prep, int nb_deg)
{
    int b   = blockIdx.x;
    int tid = threadIdx.x;
    if (b < nb_h0) {
        int idx = b * 256 + tid;
        if (idx >= N * H) return;
        int n = idx >> 6, o = idx & 63;
        const float* x = na + (size_t)n * NODE_IN;
        const float* w = Wp + (size_t)o * NODE_IN;
        float acc = bp[o];
        #pragma unroll
        for (int k = 0; k < NODE_IN; ++k) acc = fmaf(x[k], w[k], acc);
        h0[idx] = fmaxf(acc, 0.f);
    } else if (b < nb_h0 + nb_prep) {
        int t = (b - nb_h0) * 256 + tid;
        if (t < 69632) {
            // We2b: 64 x 1088, row i, col j
            int i = t / MGH, j = t % MGH;
            float v;
            if (j < 896) {
                int k = j >> 6, o = j & 63;
                v = (k < 13) ? We[(size_t)(i * 64 + o) * 13 + k] : be[i * 64 + o];
            } else {
                int jj = j - 896;                  // whhT[i][jj] = whh[jj][i]
                v = whh[(size_t)jj * 64 + i];
            }
            We2b[t] = v;
        } else if (t < 81920) {
            int u = t - 69632;
            int i = u / 192, j = u % 192;
            wihT[u] = wih[(size_t)j * 64 + i];
        } else if (t < 278528) {
            int u = t - 81920;              // k*512 + j
            int k = u >> 9, j = u & 511;
            WlT[u] = (k < 256) ? lwih[(size_t)j * 256 + k]
                               : lwhh[(size_t)j * 128 + (k - 256)];
        } else if (t < 540672) {
            int u = t - 278528;             // k*1024 + j
            int k = u >> 10, j = u & 1023;
            WsT[u] = Ws[(size_t)j * 256 + k];
        }
    } else if (b < nb_h0 + nb_prep + nb_deg) {
        int e = (b - nb_h0 - nb_prep) * 256 + tid;
        if (e < E) atomicAdd(&deg[dst[e]], 1.0f);
    } else {
        int n = (b - nb_h0 - nb_prep - nb_deg) * 256 + tid;
        if (n < N) {
            int g = gid[n];
            int p = atomicAdd(&gcnt[g], 1);
            if (p < GCAP) glist[(size_t)g * GCAP + p] = n;
        }
    }
}

// ---------------------------------------------------------------------------
// FALayer gate -> packed edge features  ef[e] = [edge_attr(12), gate, 1.0]
// one wave per edge; 128-dot reduced via shuffles
// ---------------------------------------------------------------------------
__global__ __launch_bounds__(256)
void gate_k(const float* __restrict__ h0, const float* __restrict__ ea,
            const int* __restrict__ src, const int* __restrict__ dst,
            const float* __restrict__ Wg, const float* __restrict__ bg,
            const float* __restrict__ deg, float* __restrict__ ef, int E)
{
    int e    = blockIdx.x * 4 + (threadIdx.x >> 6);
    int lane = threadIdx.x & 63;
    if (e >= E) return;
    int s = src[e], d = dst[e];
    float v = Wg[lane]      * h0[(size_t)d * H + lane]
            + Wg[H + lane]  * h0[(size_t)s * H + lane];
    #pragma unroll
    for (int off = 32; off; off >>= 1) v += __shfl_xor(v, off);
    if (lane < EF) {
        float out;
        if (lane < EDGE_IN) out = ea[(size_t)e * EDGE_IN + lane];
        else if (lane == EDGE_IN) {
            float t = tanhf(v + bg[0]);
            out = 0.3f + t * deg[d] * deg[s];
        } else out = 1.0f;
        ef[(size_t)e * EF + lane] = out;
    }
}

// ---------------------------------------------------------------------------
// per-edge message + scatter:  agg[dst] += sum_k ef[e,k] * M[src, k*64+o]
// M rows have stride MGH (fused M|gh buffer); only first 896 cols are M.
// ---------------------------------------------------------------------------
__global__ __launch_bounds__(256)
void edge_k(const float* __restrict__ M, const float* __restrict__ ef,
            const int* __restrict__ src, const int* __restrict__ dst,
            float* __restrict__ agg, int E)
{
    int e = blockIdx.x * 4 + (threadIdx.x >> 6);
    int o = threadIdx.x & 63;
    if (e >= E) return;
    int s = src[e], d = dst[e];
    const float* Ms = M + (size_t)s * MGH;
    const float* f  = ef + (size_t)e * EF;
    float m = 0.f;
    #pragma unroll
    for (int k = 0; k < EF; ++k) m = fmaf(f[k], Ms[k * H + o], m);
    atomicAdd(&agg[(size_t)d * H + o], m);
}

// ---------------------------------------------------------------------------
// GRU elementwise (torch gate order r,z,n); biases folded here.
// gh rows live at stride ghld (columns 896.. of the fused M|gh buffer).
// Also re-zeroes agg[idx] for the NEXT message-passing step (the only
// consumer of agg, the gi-GEMM, has already run in this step).
// ---------------------------------------------------------------------------
__global__ __launch_bounds__(256)
void gru_k(const float* __restrict__ gi, const float* __restrict__ gh, int ghld,
           const float* __restrict__ bih, const float* __restrict__ bhh,
           const float* __restrict__ hin, float* __restrict__ hout,
           float* __restrict__ agg, int N)
{
    int idx = blockIdx.x * 256 + threadIdx.x;
    if (idx >= N * H) return;
    int n = idx >> 6, o = idx & 63;
    const float* gin = gi + (size_t)n * 192;
    const float* ghn = gh + (size_t)n * ghld;
    float r  = sigmoidf(gin[o]       + bih[o]       + ghn[o]       + bhh[o]);
    float z  = sigmoidf(gin[64 + o]  + bih[64 + o]  + ghn[64 + o]  + bhh[64 + o]);
    float gn = ghn[128 + o] + bhh[128 + o];
    float ng = tanhf(gin[128 + o] + bih[128 + o] + r * gn);
    float hv = hin[idx];
    hout[idx] = (1.f - z) * ng + z * hv;
    agg[idx]  = 0.f;
}

// ---------------------------------------------------------------------------
// Fused Set2Set inner step: LSTM elementwise + attention + softmax + readout.
// One 64-thread block (single wave) per graph.
// Writes Acat[b] = [q (128) | readout (128) | hl (128)].
// ---------------------------------------------------------------------------
__global__ __launch_bounds__(64)
void att_k(const float* __restrict__ h0, const float* __restrict__ h,
           const float* __restrict__ g4,
           const float* __restrict__ lbih, const float* __restrict__ lbhh,
           float* __restrict__ cl,
           const int* __restrict__ glist, const int* __restrict__ gcnt,
           float* __restrict__ Acat)
{
    int b    = blockIdx.x;
    int lane = threadIdx.x;
    __shared__ float q[128];
    __shared__ float sc[GCAP];

    // ---- LSTM elementwise (gate order i,f,g,o), d = lane and lane+64
    const float* g = g4 + (size_t)b * 512;
    #pragma unroll
    for (int t = 0; t < 2; ++t) {
        int d = lane + t * 64;
        float ii = sigmoidf(g[d]       + lbih[d]       + lbhh[d]);
        float ff = sigmoidf(g[128 + d] + lbih[128 + d] + lbhh[128 + d]);
        float gg = tanhf  (g[256 + d] + lbih[256 + d] + lbhh[256 + d]);
        float oo = sigmoidf(g[384 + d] + lbih[384 + d] + lbhh[384 + d]);
        float c  = ff * cl[(size_t)b * 128 + d] + ii * gg;
        cl[(size_t)b * 128 + d] = c;
        q[d] = oo * tanhf(c);
    }
    __syncthreads();

    int c = gcnt[b]; if (c > GCAP) c = GCAP;

    // ---- scores + max
    float lmax = -INFINITY;
    for (int i = lane; i < c; i += 64) {
        int n = glist[(size_t)b * GCAP + i];
        const float* f0 = h0 + (size_t)n * H;
        const float* f1 = h  + (size_t)n * H;
        float s = 0.f;
        #pragma unroll
        for (int j = 0; j < H; ++j) s = fmaf(f0[j], q[j], s);
        #pragma unroll
        for (int j = 0; j < H; ++j) s = fmaf(f1[j], q[H + j], s);
        sc[i] = s;
        lmax = fmaxf(lmax, s);
    }
    #pragma unroll
    for (int off = 32; off; off >>= 1) lmax = fmaxf(lmax, __shfl_xor(lmax, off));

    // ---- exp + sum
    float lsum = 0.f;
    for (int i = lane; i < c; i += 64) {
        float e = expf(sc[i] - lmax);
        sc[i] = e;
        lsum += e;
    }
    #pragma unroll
    for (int off = 32; off; off >>= 1) lsum += __shfl_xor(lsum, off);
    __syncthreads();

    // ---- weighted readout
    float inv = 1.f / lsum;
    float r0 = 0.f, r1 = 0.f;
    for (int i = 0; i < c; ++i) {
        int n = glist[(size_t)b * GCAP + i];
        float w = sc[i];
        r0 = fmaf(w, h0[(size_t)n * H + lane], r0);
        r1 = fmaf(w, h [(size_t)n * H + lane], r1);
    }
    float* A = Acat + (size_t)b * 384;
    A[lane]       = q[lane];            // q_star[:128] = q
    A[64 + lane]  = q[64 + lane];
    A[128 + lane] = r0 * inv;           // q_star[128:256] = readout
    A[192 + lane] = r1 * inv;
    A[256 + lane] = q[lane];            // hl (LSTM recurrent input)
    A[320 + lane] = q[64 + lane];
}

// ---------------------------------------------------------------------------
extern "C" void kernel_launch(void* const* d_in, const int* in_sizes, int n_in,
                              void* d_out, int out_size, void* d_ws, size_t ws_size,
                              hipStream_t stream)
{
    (void)n_in; (void)ws_size;
    const float* node_attr = (const float*)d_in[0];
    const float* edge_attr = (const float*)d_in[1];
    const int*   src       = (const int*)d_in[2];
    const int*   dst       = (const int*)d_in[3];
    const int*   gid       = (const int*)d_in[4];
    const float* Wp        = (const float*)d_in[6];
    const float* bp        = (const float*)d_in[7];
    const float* Wg        = (const float*)d_in[8];
    const float* bg        = (const float*)d_in[9];
    const float* We        = (const float*)d_in[10];
    const float* be        = (const float*)d_in[11];
    const float* nb        = (const float*)d_in[12];
    const float* gwih      = (const float*)d_in[13];
    const float* gwhh      = (const float*)d_in[14];
    const float* gbih      = (const float*)d_in[15];
    const float* gbhh      = (const float*)d_in[16];
    const float* lwih      = (const float*)d_in[17];
    const float* lwhh      = (const float*)d_in[18];
    const float* lbih      = (const float*)d_in[19];
    const float* lbhh      = (const float*)d_in[20];
    const float* Ws        = (const float*)d_in[21];
    const float* bs        = (const float*)d_in[22];
    const float* pa        = (const float*)d_in[23];

    const int N = in_sizes[0] / NODE_IN;   // 10000
    const int E = in_sizes[2];             // 40000
    const int B = out_size / 1024;         // 250

    // ---- workspace layout (floats), 64-float aligned ------------------------
    float* ws = (float*)d_ws;
    size_t off = 0;
    auto alloc = [&](size_t n) { size_t o = off; off += (n + 63) & ~(size_t)63; return o; };
    // zeroed-at-start region (contiguous): deg, cl, Acat, gcnt, agg
    size_t oDEG  = alloc(N);
    size_t oCL   = alloc((size_t)B * 128);
    size_t oACAT = alloc((size_t)B * 384);
    size_t oGCNT = alloc(B);                     // int
    size_t oAGG  = alloc((size_t)N * H);
    size_t zero_beg = oDEG, zero_end = off;
    size_t oH0   = alloc((size_t)N * H);
    size_t oHB   = alloc((size_t)N * H);
    size_t oEF   = alloc((size_t)E * EF);
    size_t oGL   = alloc((size_t)B * GCAP);      // int
    size_t oWE2  = alloc(64 * MGH);              // fused [We2 | whhT]
    size_t oWIHT = alloc(64 * 192);
    size_t oWLT  = alloc(384 * 512);
    size_t oWST  = alloc(256 * 1024);
    size_t oG4   = alloc((size_t)B * 512);
    size_t oGI   = alloc((size_t)N * 192);
    size_t oM    = alloc((size_t)N * MGH);       // fused M|gh, 10000 x 1088

    float* deg  = ws + oDEG;
    float* clb  = ws + oCL;
    float* Acat = ws + oACAT;
    int*   gcnt = (int*)(ws + oGCNT);
    float* agg  = ws + oAGG;
    float* h0   = ws + oH0;
    float* hbuf = ws + oHB;
    float* ef   = ws + oEF;
    int*   glist= (int*)(ws + oGL);
    float* We2b = ws + oWE2;
    float* wihT = ws + oWIHT;
    float* WlT  = ws + oWLT;
    float* WsT  = ws + oWST;
    float* g4   = ws + oG4;
    float* gib  = ws + oGI;
    float* Mb   = ws + oM;
    float* ghb  = Mb + 896;                      // gh = cols 896..1087 of M|gh

    const int mt = (N + 63) / 64;   // row tiles for node GEMMs (157)
    const int bt = (B + 63) / 64;   // row tiles for graph GEMMs (4)

    // ---- init + fused prologue ---------------------------------------------
    hipMemsetAsync(ws + zero_beg, 0, (zero_end - zero_beg) * sizeof(float), stream);
    const int nb_h0   = (N * H + 255) / 256;     // 2500
    const int nb_prep = (540672 + 255) / 256;    // 2112
    const int nb_deg  = (E + 255) / 256;         // 157
    const int nb_gl   = (N + 255) / 256;         // 40
    prep_all_k<<<nb_h0 + nb_prep + nb_deg + nb_gl, 256, 0, stream>>>(
        node_attr, Wp, bp, h0, We, be, gwih, gwhh, lwih, lwhh, Ws,
        We2b, wihT, WlT, WsT, dst, deg, gid, gcnt, glist,
        N, E, nb_h0, nb_prep, nb_deg);
    gate_k<<<(E + 3) / 4, 256, 0, stream>>>(h0, edge_attr, src, dst, Wg, bg, deg, ef, E);

    // ---- 3 message-passing steps -------------------------------------------
    const float* hcur = h0;
    for (int step = 0; step < 3; ++step) {
        // fused [M | gh] = hcur @ [We2 | whhT]   (N x 1088, K=64)
        gemm_k<0, 0><<<dim3(mt, MGH / 64), 256, 0, stream>>>(
            hcur, H, We2b, MGH, Mb, MGH, N, MGH, 64, nullptr, nullptr, nullptr);
        edge_k<<<(E + 3) / 4, 256, 0, stream>>>(Mb, ef, src, dst, agg, E);
        gemm_k<1, 0><<<dim3(mt, 3), 256, 0, stream>>>(agg, H, wihT, 192, gib, 192,
                                                      N, 192, 64, nb, nullptr, nullptr);
        gru_k<<<(N * H + 255) / 256, 256, 0, stream>>>(gib, ghb, MGH, gbih, gbhh,
                                                       hcur, hbuf, agg, N);
        hcur = hbuf;
    }

    // ---- 3 Set2Set steps (LSTM fused into att_k) ---------------------------
    for (int s = 0; s < 3; ++s) {
        gemm_k<0, 0><<<dim3(bt, 8), 256, 0, stream>>>(Acat, 384, WlT, 512, g4, 512,
                                                      B, 512, 384, nullptr, nullptr, nullptr);
        att_k<<<B, 64, 0, stream>>>(h0, hbuf, g4, lbih, lbhh, clb, glist, gcnt, Acat);
    }

    // ---- final projection + PReLU ------------------------------------------
    gemm_k<0, 1><<<dim3(bt, 16), 256, 0, stream>>>(Acat, 384, WsT, 1024, (float*)d_out, 1024,
                                                   B, 1024, 256, nullptr, bs, pa);
}